// Round 1
// baseline (4083.452 us; speedup 1.0000x reference)
//
#include <hip/hip_runtime.h>
#include <math.h>

// Problem constants (verified against in_sizes at runtime where cheap)
#define DD 128
#define EAD 96
#define EPB 8   // edges per block (256 threads / 32 lanes per edge)

// ---------------------------------------------------------------------------
// Fused 4-way GEMM: O_y = X @ W_y + b_y for y in {q,k,v,skip}; K=N=128.
// Tile: 32 rows x 128 cols, full W in LDS (64KB) + X tile (16KB).
// ---------------------------------------------------------------------------
__global__ __launch_bounds__(256) void gemm4_kernel(
    const float* __restrict__ X,
    const float* __restrict__ W0, const float* __restrict__ W1,
    const float* __restrict__ W2, const float* __restrict__ W3,
    const float* __restrict__ b0, const float* __restrict__ b1,
    const float* __restrict__ b2, const float* __restrict__ b3,
    float* __restrict__ O0, float* __restrict__ O1,
    float* __restrict__ O2, float* __restrict__ O3, int M)
{
    __shared__ float Xs[32 * 128];
    __shared__ float Wsh[128 * 128];
    const int which = blockIdx.y;
    const float* W    = (which == 0) ? W0 : (which == 1) ? W1 : (which == 2) ? W2 : W3;
    const float* bias = (which == 0) ? b0 : (which == 1) ? b1 : (which == 2) ? b2 : b3;
    float* O          = (which == 0) ? O0 : (which == 1) ? O1 : (which == 2) ? O2 : O3;
    const int tid = threadIdx.x;
    const int m0 = blockIdx.x * 32;

    {   // stage W (4096 float4)
        const float4* Wg = (const float4*)W;
        float4* Wl = (float4*)Wsh;
        #pragma unroll
        for (int i = 0; i < 16; ++i) Wl[tid + i * 256] = Wg[tid + i * 256];
    }
    {   // stage X tile (1024 float4), zero-pad OOB rows
        float4* Xl = (float4*)Xs;
        const float4* Xg = (const float4*)X;
        #pragma unroll
        for (int i = 0; i < 4; ++i) {
            int f = tid + i * 256;
            int r = f >> 5, c4 = f & 31;
            int row = m0 + r;
            float4 val = make_float4(0.f, 0.f, 0.f, 0.f);
            if (row < M) val = Xg[(size_t)row * 32 + c4];
            Xl[f] = val;
        }
    }
    __syncthreads();

    const int tr = tid >> 5, tc = tid & 31;
    const int r0 = tr * 4, c0 = tc * 4;
    float acc[4][4] = {};
    #pragma unroll 4
    for (int kk = 0; kk < 128; ++kk) {
        float4 bb = *(const float4*)&Wsh[kk * 128 + c0];
        #pragma unroll
        for (int i = 0; i < 4; ++i) {
            float a = Xs[(r0 + i) * 128 + kk];
            acc[i][0] += a * bb.x; acc[i][1] += a * bb.y;
            acc[i][2] += a * bb.z; acc[i][3] += a * bb.w;
        }
    }
    float4 bias4 = *(const float4*)&bias[c0];
    #pragma unroll
    for (int i = 0; i < 4; ++i) {
        int row = m0 + r0 + i;
        if (row < M) {
            float4 o;
            o.x = acc[i][0] + bias4.x; o.y = acc[i][1] + bias4.y;
            o.z = acc[i][2] + bias4.z; o.w = acc[i][3] + bias4.w;
            ((float4*)O)[(size_t)row * 32 + tc] = o;
        }
    }
}

// ---------------------------------------------------------------------------
// Edge pass: per edge compute edge_attr (32 cos + 64 msg), e = ea @ We,
// alpha_h = <q[dst], k[src]+e>_h / 8, w = exp(alpha), then atomically
// accumulate den[dst,h] += w and acc[dst,:] += w*(v[src]+e).
// 32 lanes per edge (4 channels each), 8 edges per 256-thread block.
// ---------------------------------------------------------------------------
__global__ __launch_bounds__(256) void edge_pass_kernel(
    const int* __restrict__ ei, const float* __restrict__ last_update,
    const float* __restrict__ tarr, const float* __restrict__ msg,
    const float* __restrict__ time_w, const float* __restrict__ time_b,
    const float* __restrict__ We,
    const float* __restrict__ q, const float* __restrict__ k,
    const float* __restrict__ v,
    float* __restrict__ acc, float* __restrict__ den, int E)
{
    __shared__ float WeS[EAD * 128];
    __shared__ float eaS[EPB][EAD];
    const int tid = threadIdx.x;
    {
        const float4* Wg = (const float4*)We;
        float4* Wl = (float4*)WeS;
        for (int i = tid; i < EAD * 32; i += 256) Wl[i] = Wg[i];
    }
    const int g = tid >> 5;
    const int lane = tid & 31;
    const float tw = time_w[lane];
    const float tb = time_b[lane];
    __syncthreads();

    const int stride = gridDim.x * EPB;
    const int nIter = (E + stride - 1) / stride;
    for (int it = 0; it < nIter; ++it) {
        int e = (it * gridDim.x + blockIdx.x) * EPB + g;
        bool valid = e < E;
        int src = 0, dst = 0;
        if (valid) {
            src = ei[e]; dst = ei[E + e];
            float rel = last_update[src] - tarr[e];
            eaS[g][lane] = cosf(rel * tw + tb);
            float2 m2 = ((const float2*)msg)[(size_t)e * 32 + lane];
            eaS[g][32 + 2 * lane] = m2.x;
            eaS[g][33 + 2 * lane] = m2.y;
        }
        __syncthreads();
        if (valid) {
            float4 ev = make_float4(0.f, 0.f, 0.f, 0.f);
            const float4* WeS4 = (const float4*)WeS;
            #pragma unroll 8
            for (int j = 0; j < EAD; ++j) {
                float a = eaS[g][j];
                float4 w4 = WeS4[j * 32 + lane];
                ev.x += a * w4.x; ev.y += a * w4.y;
                ev.z += a * w4.z; ev.w += a * w4.w;
            }
            float4 q4 = ((const float4*)q)[(size_t)dst * 32 + lane];
            float4 k4 = ((const float4*)k)[(size_t)src * 32 + lane];
            float part = q4.x * (k4.x + ev.x) + q4.y * (k4.y + ev.y)
                       + q4.z * (k4.z + ev.z) + q4.w * (k4.w + ev.w);
            part += __shfl_xor(part, 1);
            part += __shfl_xor(part, 2);
            part += __shfl_xor(part, 4);
            part += __shfl_xor(part, 8);
            // lanes 0..15 -> head 0, lanes 16..31 -> head 1
            float w = __expf(part * 0.125f);
            if ((lane & 15) == 0) atomicAdd(&den[(size_t)dst * 2 + (lane >> 4)], w);
            float4 v4 = ((const float4*)v)[(size_t)src * 32 + lane];
            float* ap = acc + (size_t)dst * 128 + 4 * lane;
            atomicAdd(ap + 0, w * (v4.x + ev.x));
            atomicAdd(ap + 1, w * (v4.y + ev.y));
            atomicAdd(ap + 2, w * (v4.z + ev.z));
            atomicAdd(ap + 3, w * (v4.w + ev.w));
        }
        __syncthreads();
    }
}

// ---------------------------------------------------------------------------
// Node finish: out = acc/den + skip; optionally accumulate BN sums.
// ---------------------------------------------------------------------------
__global__ __launch_bounds__(256) void node_finish_kernel(
    const float* __restrict__ acc, const float* __restrict__ den,
    const float* __restrict__ s, float* __restrict__ outp,
    float* __restrict__ bn_sum, float* __restrict__ bn_ssq,
    int N, int do_bn)
{
    const int c = threadIdx.x & 127;
    const int half = threadIdx.x >> 7;
    const int rpb = (N + gridDim.x - 1) / gridDim.x;
    const int r0b = blockIdx.x * rpb;
    const int r1 = min(N, r0b + rpb);
    float sum = 0.f, ssq = 0.f;
    for (int r = r0b + half; r < r1; r += 2) {
        float d = den[(size_t)r * 2 + (c >> 6)];
        float a = acc[(size_t)r * 128 + c];
        float val = (d > 0.f ? a / d : 0.f) + s[(size_t)r * 128 + c];
        outp[(size_t)r * 128 + c] = val;
        sum += val; ssq += val * val;
    }
    if (do_bn) {
        __shared__ float s1[256], s2b[256];
        s1[threadIdx.x] = sum; s2b[threadIdx.x] = ssq;
        __syncthreads();
        if (half == 0) {
            atomicAdd(&bn_sum[c], s1[c] + s1[c + 128]);
            atomicAdd(&bn_ssq[c], s2b[c] + s2b[c + 128]);
        }
    }
}

__global__ void bn_stats_kernel(const float* __restrict__ bn_sum,
                                const float* __restrict__ bn_ssq,
                                float* __restrict__ mu, float* __restrict__ inv,
                                int N)
{
    int c = threadIdx.x;
    float m = bn_sum[c] / (float)N;
    float var = bn_ssq[c] / (float)N - m * m;
    var = fmaxf(var, 0.f);
    mu[c] = m;
    inv[c] = rsqrtf(var + 1e-5f);
}

__global__ __launch_bounds__(256) void bn_apply_kernel(
    const float* __restrict__ pre, const float* __restrict__ mu,
    const float* __restrict__ inv, const float* __restrict__ gw,
    const float* __restrict__ bw, float* __restrict__ h, size_t total)
{
    size_t i = (size_t)blockIdx.x * 256 + threadIdx.x;
    const size_t stride = (size_t)gridDim.x * 256;
    for (; i < total; i += stride) {
        int c = (int)(i & 127);
        float val = (pre[i] - mu[c]) * inv[c] * gw[c] + bw[c];
        h[i] = fmaxf(val, 0.f);
    }
}

// ---------------------------------------------------------------------------
extern "C" void kernel_launch(void* const* d_in, const int* in_sizes, int n_in,
                              void* d_out, int out_size, void* d_ws, size_t ws_size,
                              hipStream_t stream)
{
    const float* x   = (const float*)d_in[0];
    const float* lu  = (const float*)d_in[1];
    const int*   ei  = (const int*)d_in[2];
    const float* t   = (const float*)d_in[3];
    const float* msg = (const float*)d_in[4];
    const float* tw  = (const float*)d_in[5];
    const float* tb  = (const float*)d_in[6];
    const float* bng = (const float*)d_in[7];
    const float* bnb = (const float*)d_in[8];
    const float* Wq1 = (const float*)d_in[9];  const float* bq1 = (const float*)d_in[10];
    const float* Wk1 = (const float*)d_in[11]; const float* bk1 = (const float*)d_in[12];
    const float* Wv1 = (const float*)d_in[13]; const float* bv1 = (const float*)d_in[14];
    const float* We1 = (const float*)d_in[15];
    const float* Ws1 = (const float*)d_in[16]; const float* bs1 = (const float*)d_in[17];
    const float* Wq2 = (const float*)d_in[18]; const float* bq2 = (const float*)d_in[19];
    const float* Wk2 = (const float*)d_in[20]; const float* bk2 = (const float*)d_in[21];
    const float* Wv2 = (const float*)d_in[22]; const float* bv2 = (const float*)d_in[23];
    const float* We2 = (const float*)d_in[24];
    const float* Ws2 = (const float*)d_in[25]; const float* bs2 = (const float*)d_in[26];

    const int N = in_sizes[0] / DD;
    const int E = in_sizes[3];
    const size_t NM = (size_t)N * DD;

    float* ws   = (float*)d_ws;
    float* qb   = ws;            // q
    float* kb   = ws + NM;       // k  (later: h post-BN)
    float* vb   = ws + 2 * NM;   // v  (later: conv1 pre-BN output)
    float* sb   = ws + 3 * NM;   // skip
    float* ab   = ws + 4 * NM;   // attention numerator accumulator
    float* hb   = ws + 5 * NM;   // h post BN+ReLU
    float* den  = ws + 6 * NM;   // [N,2]
    float* bsum = den + (size_t)2 * N;   // [128]
    float* bssq = bsum + 128;            // [128]
    float* muv  = bssq + 128;            // [128]
    float* invv = muv + 128;             // [128]

    dim3 gemmGrid((N + 31) / 32, 4);

    // ---------------- layer 1 ----------------
    hipMemsetAsync(ab, 0, NM * sizeof(float), stream);
    hipMemsetAsync(den, 0, ((size_t)2 * N + 256) * sizeof(float), stream);
    gemm4_kernel<<<gemmGrid, 256, 0, stream>>>(
        x, Wq1, Wk1, Wv1, Ws1, bq1, bk1, bv1, bs1, qb, kb, vb, sb, N);
    edge_pass_kernel<<<768, 256, 0, stream>>>(
        ei, lu, t, msg, tw, tb, We1, qb, kb, vb, ab, den, E);
    // conv1 pre-BN output into vb (v is dead now); accumulate BN sums
    node_finish_kernel<<<256, 256, 0, stream>>>(ab, den, sb, vb, bsum, bssq, N, 1);
    bn_stats_kernel<<<1, 128, 0, stream>>>(bsum, bssq, muv, invv, N);
    bn_apply_kernel<<<2048, 256, 0, stream>>>(vb, muv, invv, bng, bnb, hb, NM);

    // ---------------- layer 2 ----------------
    hipMemsetAsync(ab, 0, NM * sizeof(float), stream);
    hipMemsetAsync(den, 0, (size_t)2 * N * sizeof(float), stream);
    gemm4_kernel<<<gemmGrid, 256, 0, stream>>>(
        hb, Wq2, Wk2, Wv2, Ws2, bq2, bk2, bv2, bs2, qb, kb, vb, sb, N);
    edge_pass_kernel<<<768, 256, 0, stream>>>(
        ei, lu, t, msg, tw, tb, We2, qb, kb, vb, ab, den, E);
    node_finish_kernel<<<256, 256, 0, stream>>>(
        ab, den, sb, (float*)d_out, nullptr, nullptr, N, 0);
}

// Round 2
// 2044.438 us; speedup vs baseline: 1.9973x; 1.9973x over previous
//
#include <hip/hip_runtime.h>
#include <math.h>

#define DD 128

// ======================= CSR build (once per call) =======================
__global__ __launch_bounds__(256) void hist_kernel(const int* __restrict__ ei,
                                                   int* __restrict__ cnt, int E) {
    int i = blockIdx.x * 256 + threadIdx.x;
    if (i < E) atomicAdd(&cnt[ei[E + i]], 1);
}

__global__ __launch_bounds__(1024) void scan_kernel(const int* __restrict__ cnt,
                                                    int* __restrict__ row_start,
                                                    int* __restrict__ cursor, int N) {
    __shared__ int part[1024];
    const int tid = threadIdx.x;
    const int chunk = (N + 1023) >> 10;
    const int lo = min(N, tid * chunk);
    const int hi = min(N, lo + chunk);
    int s = 0;
    for (int i = lo; i < hi; ++i) s += cnt[i];
    part[tid] = s;
    __syncthreads();
    for (int off = 1; off < 1024; off <<= 1) {
        int val = 0;
        if (tid >= off) val = part[tid - off];
        __syncthreads();
        part[tid] += val;
        __syncthreads();
    }
    int run = (tid == 0) ? 0 : part[tid - 1];
    for (int i = lo; i < hi; ++i) {
        row_start[i] = run; cursor[i] = run;
        run += cnt[i];
    }
    if (tid == 1023) row_start[N] = part[1023];
}

__global__ __launch_bounds__(256) void scatter_kernel(
    const int* __restrict__ ei, const float* __restrict__ lu, const float* __restrict__ t,
    int* __restrict__ cursor, int* __restrict__ perm, int* __restrict__ srcp,
    float* __restrict__ relp, int E)
{
    int i = blockIdx.x * 256 + threadIdx.x;
    if (i < E) {
        int s = ei[i], d = ei[E + i];
        int pos = atomicAdd(&cursor[d], 1);
        perm[pos] = i;
        srcp[pos] = s;
        relp[pos] = lu[s] - t[i];
    }
}

// ======================= Wu = Wq @ B,  bu = bq @ B =======================
// B bakes the per-head q->u projection AND the lane-friendly permutation:
// u_pad[n][h][l] = float4( u_h[l], u_h[32+2l], u_h[33+2l], 0 ),
// u_h[j] = sum_c q_h[c] * We[j][h*64+c].
__global__ __launch_bounds__(256) void build_wu_kernel(
    const float* __restrict__ Wq, const float* __restrict__ bq,
    const float* __restrict__ We, float* __restrict__ Wu, float* __restrict__ bu)
{
    int idx = blockIdx.x * 256 + threadIdx.x;   // [0, 32768)
    int h = idx >> 14;
    int r = (idx >> 7) & 127;
    int col = idx & 127;
    int l = col >> 2, kk = col & 3;
    int dim = (kk == 0) ? l : (kk == 1) ? (32 + 2 * l) : (33 + 2 * l);
    float s = 0.f, sb = 0.f;
    if (kk < 3) {
        for (int c = 0; c < 64; ++c) {
            float wv = We[dim * 128 + h * 64 + c];
            s += Wq[r * 128 + h * 64 + c] * wv;
            if (r == 0) sb += bq[h * 64 + c] * wv;
        }
    }
    Wu[(h * 128 + r) * 128 + col] = s;
    if (r == 0) bu[h * 128 + col] = sb;
}

// ======================= fused 6-way node GEMM (K=128, N=128) ============
__global__ __launch_bounds__(256) void gemm6_kernel(
    const float* __restrict__ X,
    const float* __restrict__ W0, const float* __restrict__ W1,
    const float* __restrict__ W2, const float* __restrict__ W3,
    const float* __restrict__ W4, const float* __restrict__ W5,
    const float* __restrict__ b0, const float* __restrict__ b1,
    const float* __restrict__ b2, const float* __restrict__ b3,
    const float* __restrict__ b4, const float* __restrict__ b5,
    float* __restrict__ O0, float* __restrict__ O1,
    float* __restrict__ O2, float* __restrict__ O3,
    float* __restrict__ O4, float* __restrict__ O5, int M)
{
    __shared__ float Xs[32 * 128];
    __shared__ float Wsh[128 * 128];
    const int which = blockIdx.y;
    const float* W; const float* bias; float* O; int ostr;  // ostr in float4 units
    switch (which) {
        case 0: W = W0; bias = b0; O = O0; ostr = 32; break;
        case 1: W = W1; bias = b1; O = O1; ostr = 32; break;
        case 2: W = W2; bias = b2; O = O2; ostr = 32; break;
        case 3: W = W3; bias = b3; O = O3; ostr = 32; break;
        case 4: W = W4; bias = b4; O = O4; ostr = 64; break;
        default: W = W5; bias = b5; O = O5; ostr = 64; break;
    }
    const int tid = threadIdx.x;
    const int m0 = blockIdx.x * 32;

    {
        const float4* Wg = (const float4*)W;
        float4* Wl = (float4*)Wsh;
        #pragma unroll
        for (int i = 0; i < 16; ++i) Wl[tid + i * 256] = Wg[tid + i * 256];
    }
    {
        float4* Xl = (float4*)Xs;
        const float4* Xg = (const float4*)X;
        #pragma unroll
        for (int i = 0; i < 4; ++i) {
            int f = tid + i * 256;
            int r = f >> 5, c4 = f & 31;
            int row = m0 + r;
            float4 val = make_float4(0.f, 0.f, 0.f, 0.f);
            if (row < M) val = Xg[(size_t)row * 32 + c4];
            Xl[f] = val;
        }
    }
    __syncthreads();

    const int tr = tid >> 5, tc = tid & 31;
    const int r0 = tr * 4, c0 = tc * 4;
    float acc[4][4] = {};
    #pragma unroll 4
    for (int kk = 0; kk < 128; ++kk) {
        float4 bb = *(const float4*)&Wsh[kk * 128 + c0];
        #pragma unroll
        for (int i = 0; i < 4; ++i) {
            float a = Xs[(r0 + i) * 128 + kk];
            acc[i][0] += a * bb.x; acc[i][1] += a * bb.y;
            acc[i][2] += a * bb.z; acc[i][3] += a * bb.w;
        }
    }
    float4 bias4 = *(const float4*)&bias[c0];
    #pragma unroll
    for (int i = 0; i < 4; ++i) {
        int row = m0 + r0 + i;
        if (row < M) {
            float4 o;
            o.x = acc[i][0] + bias4.x; o.y = acc[i][1] + bias4.y;
            o.z = acc[i][2] + bias4.z; o.w = acc[i][3] + bias4.w;
            ((float4*)O)[(size_t)row * ostr + tc] = o;
        }
    }
}

// ======================= node-centric attention ==========================
// One 32-lane group per node. Per edge: alpha_h = (q.k + ea.u_h)/8, w=exp.
// Accumulate den_h, wv (128), sea_h (96, lane-distributed). Finish:
// out = (wv + sea_h @ We_h)/den_h + skip, plus optional BN sums.
__global__ __launch_bounds__(256) void node_attn_kernel(
    const int* __restrict__ row_start, const int* __restrict__ perm,
    const int* __restrict__ srcp, const float* __restrict__ relp,
    const float* __restrict__ msg,
    const float* __restrict__ time_w, const float* __restrict__ time_b,
    const float* __restrict__ q, const float* __restrict__ k,
    const float* __restrict__ v, const float* __restrict__ u,
    const float* __restrict__ We, const float* __restrict__ skip,
    float* __restrict__ outp, float* __restrict__ bn_sum, float* __restrict__ bn_ssq,
    int N, int do_bn)
{
    __shared__ float WeS[96 * 128];   // 48 KB
    const int tid = threadIdx.x;
    {
        const float4* Wg = (const float4*)We;
        float4* Wl = (float4*)WeS;
        #pragma unroll
        for (int i = 0; i < 12; ++i) Wl[tid + i * 256] = Wg[tid + i * 256];
    }
    const int g = tid >> 5, l = tid & 31;
    const float twl = time_w[l];
    const float tbl = time_b[l];
    __syncthreads();

    const float4* K4 = (const float4*)k;
    const float4* V4 = (const float4*)v;
    const float4* Q4 = (const float4*)q;
    const float4* U4 = (const float4*)u;
    const float2* M2 = (const float2*)msg;
    const float4* S4 = (const float4*)skip;
    const float4* WeS4 = (const float4*)WeS;

    float4 bsum = {0,0,0,0}, bssq = {0,0,0,0};

    for (int n = blockIdx.x * 8 + g; n < N; n += gridDim.x * 8) {
        const int e0 = row_start[n], e1 = row_start[n + 1];
        const float4 q4 = Q4[(size_t)n * 32 + l];
        const float4 u0 = U4[(size_t)n * 64 + l];
        const float4 u1 = U4[(size_t)n * 64 + 32 + l];
        float4 wv = {0,0,0,0};
        float sea0x = 0.f, sea0y = 0.f, sea0z = 0.f;
        float sea1x = 0.f, sea1y = 0.f, sea1z = 0.f;
        float den0 = 0.f, den1 = 0.f;

        for (int i = e0; i < e1; ++i) {
            const int eid = perm[i];
            const int src = srcp[i];
            const float rel = relp[i];
            const float ea_c = cosf(rel * twl + tbl);           // ea dim l
            const float2 m2 = M2[(size_t)eid * 32 + l];          // ea dims 32+2l,33+2l
            const float4 k4 = K4[(size_t)src * 32 + l];
            // q.k per head (lanes 0-15 = head0 channels, 16-31 = head1)
            float p = q4.x*k4.x + q4.y*k4.y + q4.z*k4.z + q4.w*k4.w;
            p += __shfl_xor(p, 1); p += __shfl_xor(p, 2);
            p += __shfl_xor(p, 4); p += __shfl_xor(p, 8);
            const float po = __shfl_xor(p, 16);
            const float qk0 = (l < 16) ? p : po;
            const float qk1 = (l < 16) ? po : p;
            // ea.u per head
            float p0 = ea_c*u0.x + m2.x*u0.y + m2.y*u0.z;
            float p1 = ea_c*u1.x + m2.x*u1.y + m2.y*u1.z;
            p0 += __shfl_xor(p0, 1); p0 += __shfl_xor(p0, 2);
            p0 += __shfl_xor(p0, 4); p0 += __shfl_xor(p0, 8); p0 += __shfl_xor(p0, 16);
            p1 += __shfl_xor(p1, 1); p1 += __shfl_xor(p1, 2);
            p1 += __shfl_xor(p1, 4); p1 += __shfl_xor(p1, 8); p1 += __shfl_xor(p1, 16);
            const float w0 = __expf((qk0 + p0) * 0.125f);
            const float w1 = __expf((qk1 + p1) * 0.125f);
            den0 += w0; den1 += w1;
            const float wh = (l < 16) ? w0 : w1;
            const float4 v4 = V4[(size_t)src * 32 + l];
            wv.x += wh*v4.x; wv.y += wh*v4.y; wv.z += wh*v4.z; wv.w += wh*v4.w;
            sea0x += w0*ea_c; sea0y += w0*m2.x; sea0z += w0*m2.y;
            sea1x += w1*ea_c; sea1y += w1*m2.x; sea1z += w1*m2.y;
        }

        // e_fin[c] = sum_j sea_h[j] * We[j][h*64+c]  (lane's 4 channels)
        float4 ef = {0,0,0,0};
        #pragma unroll
        for (int j = 0; j < 96; ++j) {
            const int owner = (j < 32) ? j : ((j - 32) >> 1);
            float c0, c1;
            if (j < 32)                    { c0 = sea0x; c1 = sea1x; }
            else if (((j - 32) & 1) == 0)  { c0 = sea0y; c1 = sea1y; }
            else                           { c0 = sea0z; c1 = sea1z; }
            const float s0 = __shfl(c0, owner, 32);
            const float s1 = __shfl(c1, owner, 32);
            const float sj = (l < 16) ? s0 : s1;
            const float4 w4 = WeS4[j * 32 + l];
            ef.x += sj*w4.x; ef.y += sj*w4.y; ef.z += sj*w4.z; ef.w += sj*w4.w;
        }

        const float dh = (l < 16) ? den0 : den1;
        const float4 s4 = S4[(size_t)n * 32 + l];
        float4 o;
        if (dh > 0.f) {
            const float r = 1.0f / dh;
            o.x = (wv.x + ef.x) * r + s4.x;
            o.y = (wv.y + ef.y) * r + s4.y;
            o.z = (wv.z + ef.z) * r + s4.z;
            o.w = (wv.w + ef.w) * r + s4.w;
        } else {
            o = s4;
        }
        ((float4*)outp)[(size_t)n * 32 + l] = o;
        if (do_bn) {
            bsum.x += o.x; bsum.y += o.y; bsum.z += o.z; bsum.w += o.w;
            bssq.x += o.x*o.x; bssq.y += o.y*o.y; bssq.z += o.z*o.z; bssq.w += o.w*o.w;
        }
    }

    if (do_bn) {
        __syncthreads();                 // WeS no longer needed: reuse as scratch
        float* red = WeS;
        const int t8 = tid * 8;
        red[t8+0]=bsum.x; red[t8+1]=bsum.y; red[t8+2]=bsum.z; red[t8+3]=bsum.w;
        red[t8+4]=bssq.x; red[t8+5]=bssq.y; red[t8+6]=bssq.z; red[t8+7]=bssq.w;
        __syncthreads();
        if (g == 0) {
            float a[8] = {0,0,0,0,0,0,0,0};
            for (int gg = 0; gg < 8; ++gg) {
                const float* r2 = &red[(gg*32 + l)*8];
                #pragma unroll
                for (int kk = 0; kk < 8; ++kk) a[kk] += r2[kk];
            }
            #pragma unroll
            for (int kk = 0; kk < 4; ++kk) {
                atomicAdd(&bn_sum[4*l + kk], a[kk]);
                atomicAdd(&bn_ssq[4*l + kk], a[4 + kk]);
            }
        }
    }
}

// ======================= BN =======================
__global__ void bn_stats_kernel(const float* __restrict__ bn_sum,
                                const float* __restrict__ bn_ssq,
                                float* __restrict__ mu, float* __restrict__ inv, int N)
{
    int c = threadIdx.x;
    float m = bn_sum[c] / (float)N;
    float var = bn_ssq[c] / (float)N - m * m;
    var = fmaxf(var, 0.f);
    mu[c] = m;
    inv[c] = rsqrtf(var + 1e-5f);
}

__global__ __launch_bounds__(256) void bn_apply_kernel(
    const float* __restrict__ pre, const float* __restrict__ mu,
    const float* __restrict__ inv, const float* __restrict__ gw,
    const float* __restrict__ bw, float* __restrict__ h, size_t total)
{
    size_t i = (size_t)blockIdx.x * 256 + threadIdx.x;
    const size_t stride = (size_t)gridDim.x * 256;
    for (; i < total; i += stride) {
        int c = (int)(i & 127);
        float val = (pre[i] - mu[c]) * inv[c] * gw[c] + bw[c];
        h[i] = fmaxf(val, 0.f);
    }
}

// =========================================================================
extern "C" void kernel_launch(void* const* d_in, const int* in_sizes, int n_in,
                              void* d_out, int out_size, void* d_ws, size_t ws_size,
                              hipStream_t stream)
{
    const float* x   = (const float*)d_in[0];
    const float* lu  = (const float*)d_in[1];
    const int*   ei  = (const int*)d_in[2];
    const float* t   = (const float*)d_in[3];
    const float* msg = (const float*)d_in[4];
    const float* tw  = (const float*)d_in[5];
    const float* tb  = (const float*)d_in[6];
    const float* bng = (const float*)d_in[7];
    const float* bnb = (const float*)d_in[8];
    const float* Wq1 = (const float*)d_in[9];  const float* bq1 = (const float*)d_in[10];
    const float* Wk1 = (const float*)d_in[11]; const float* bk1 = (const float*)d_in[12];
    const float* Wv1 = (const float*)d_in[13]; const float* bv1 = (const float*)d_in[14];
    const float* We1 = (const float*)d_in[15];
    const float* Ws1 = (const float*)d_in[16]; const float* bs1 = (const float*)d_in[17];
    const float* Wq2 = (const float*)d_in[18]; const float* bq2 = (const float*)d_in[19];
    const float* Wk2 = (const float*)d_in[20]; const float* bk2 = (const float*)d_in[21];
    const float* Wv2 = (const float*)d_in[22]; const float* bv2 = (const float*)d_in[23];
    const float* We2 = (const float*)d_in[24];
    const float* Ws2 = (const float*)d_in[25]; const float* bs2 = (const float*)d_in[26];

    const int N = in_sizes[0] / DD;
    const int E = in_sizes[3];
    const size_t NM = (size_t)N * DD;

    float* ws  = (float*)d_ws;
    float* qb  = ws;
    float* kb  = ws + NM;
    float* vb  = ws + 2 * NM;
    float* sb  = ws + 3 * NM;
    float* ub  = ws + 4 * NM;        // 2*NM: [N][2][32] float4
    float* pre = ws + 6 * NM;        // layer-1 pre-BN out; BN applied in place
    float* relp = ws + 7 * NM;       // E floats
    float* Wu   = relp + E;          // 2*128*128
    float* bu   = Wu + 32768;        // 256
    float* bsum = bu + 256;          // 128
    float* bssq = bsum + 128;        // 128
    float* muv  = bssq + 128;        // 128
    float* invv = muv + 128;         // 128
    int* cnt       = (int*)(invv + 128);
    int* row_start = cnt + N;        // N+1
    int* cursor    = row_start + N + 1;
    int* perm      = cursor + N;     // E
    int* srcp      = perm + E;       // E

    const int EB = (E + 255) / 256;

    // ---- CSR (shared by both layers) ----
    hipMemsetAsync(cnt, 0, (size_t)N * sizeof(int), stream);
    hist_kernel<<<EB, 256, 0, stream>>>(ei, cnt, E);
    scan_kernel<<<1, 1024, 0, stream>>>(cnt, row_start, cursor, N);
    scatter_kernel<<<EB, 256, 0, stream>>>(ei, lu, t, cursor, perm, srcp, relp, E);

    dim3 gemmGrid((N + 31) / 32, 6);

    // ---------------- layer 1 ----------------
    build_wu_kernel<<<128, 256, 0, stream>>>(Wq1, bq1, We1, Wu, bu);
    gemm6_kernel<<<gemmGrid, 256, 0, stream>>>(
        x, Wq1, Wk1, Wv1, Ws1, Wu, Wu + 16384,
        bq1, bk1, bv1, bs1, bu, bu + 128,
        qb, kb, vb, sb, ub, ub + 128, N);
    hipMemsetAsync(bsum, 0, 256 * sizeof(float), stream);
    node_attn_kernel<<<1024, 256, 0, stream>>>(
        row_start, perm, srcp, relp, msg, tw, tb,
        qb, kb, vb, ub, We1, sb, pre, bsum, bssq, N, 1);
    bn_stats_kernel<<<1, 128, 0, stream>>>(bsum, bssq, muv, invv, N);
    bn_apply_kernel<<<2048, 256, 0, stream>>>(pre, muv, invv, bng, bnb, pre, NM);

    // ---------------- layer 2 ----------------
    build_wu_kernel<<<128, 256, 0, stream>>>(Wq2, bq2, We2, Wu, bu);
    gemm6_kernel<<<gemmGrid, 256, 0, stream>>>(
        pre, Wq2, Wk2, Wv2, Ws2, Wu, Wu + 16384,
        bq2, bk2, bv2, bs2, bu, bu + 128,
        qb, kb, vb, sb, ub, ub + 128, N);
    node_attn_kernel<<<1024, 256, 0, stream>>>(
        row_start, perm, srcp, relp, msg, tw, tb,
        qb, kb, vb, ub, We2, sb, (float*)d_out, nullptr, nullptr, N, 0);
}

// Round 3
// 1431.434 us; speedup vs baseline: 2.8527x; 1.4282x over previous
//
#include <hip/hip_runtime.h>
#include <math.h>

#define DD 128

// ======================= CSR build (once per call) =======================
__global__ __launch_bounds__(256) void hist_kernel(const int* __restrict__ ei,
                                                   int* __restrict__ cnt, int E) {
    int i = blockIdx.x * 256 + threadIdx.x;
    if (i < E) atomicAdd(&cnt[ei[E + i]], 1);
}

__global__ __launch_bounds__(1024) void scan_kernel(const int* __restrict__ cnt,
                                                    int* __restrict__ row_start,
                                                    int* __restrict__ cursor, int N) {
    __shared__ int part[1024];
    const int tid = threadIdx.x;
    const int chunk = (N + 1023) >> 10;
    const int lo = min(N, tid * chunk);
    const int hi = min(N, lo + chunk);
    int s = 0;
    for (int i = lo; i < hi; ++i) s += cnt[i];
    part[tid] = s;
    __syncthreads();
    for (int off = 1; off < 1024; off <<= 1) {
        int val = 0;
        if (tid >= off) val = part[tid - off];
        __syncthreads();
        part[tid] += val;
        __syncthreads();
    }
    int run = (tid == 0) ? 0 : part[tid - 1];
    for (int i = lo; i < hi; ++i) {
        row_start[i] = run; cursor[i] = run;
        run += cnt[i];
    }
    if (tid == 1023) row_start[N] = part[1023];
}

__global__ __launch_bounds__(256) void scatter_kernel(
    const int* __restrict__ ei, const float* __restrict__ lu, const float* __restrict__ t,
    int* __restrict__ cursor, int2* __restrict__ se, float* __restrict__ relp, int E)
{
    int i = blockIdx.x * 256 + threadIdx.x;
    if (i < E) {
        int s = ei[i], d = ei[E + i];
        int pos = atomicAdd(&cursor[d], 1);
        se[pos] = make_int2(s, i);
        relp[pos] = lu[s] - t[i];
    }
}

// ======================= Wu = Wq @ B,  bu = bq @ B =======================
__global__ __launch_bounds__(256) void build_wu_kernel(
    const float* __restrict__ Wq, const float* __restrict__ bq,
    const float* __restrict__ We, float* __restrict__ Wu, float* __restrict__ bu)
{
    int idx = blockIdx.x * 256 + threadIdx.x;   // [0, 32768)
    int h = idx >> 14;
    int r = (idx >> 7) & 127;
    int col = idx & 127;
    int l = col >> 2, kk = col & 3;
    int dim = (kk == 0) ? l : (kk == 1) ? (32 + 2 * l) : (33 + 2 * l);
    float s = 0.f, sb = 0.f;
    if (kk < 3) {
        for (int c = 0; c < 64; ++c) {
            float wv = We[dim * 128 + h * 64 + c];
            s += Wq[r * 128 + h * 64 + c] * wv;
            if (r == 0) sb += bq[h * 64 + c] * wv;
        }
    }
    Wu[(h * 128 + r) * 128 + col] = s;
    if (r == 0) bu[h * 128 + col] = sb;
}

// ======================= fused 6-way node GEMM (K=128, N=128) ============
__global__ __launch_bounds__(256) void gemm6_kernel(
    const float* __restrict__ X,
    const float* __restrict__ W0, const float* __restrict__ W1,
    const float* __restrict__ W2, const float* __restrict__ W3,
    const float* __restrict__ W4, const float* __restrict__ W5,
    const float* __restrict__ b0, const float* __restrict__ b1,
    const float* __restrict__ b2, const float* __restrict__ b3,
    const float* __restrict__ b4, const float* __restrict__ b5,
    float* __restrict__ O0, float* __restrict__ O1,
    float* __restrict__ O2, float* __restrict__ O3,
    float* __restrict__ O4, float* __restrict__ O5, int M)
{
    __shared__ float Xs[32 * 128];
    __shared__ float Wsh[128 * 128];
    const int which = blockIdx.y;
    const float* W; const float* bias; float* O; int ostr;  // ostr in float4 units
    switch (which) {
        case 0: W = W0; bias = b0; O = O0; ostr = 32; break;
        case 1: W = W1; bias = b1; O = O1; ostr = 32; break;
        case 2: W = W2; bias = b2; O = O2; ostr = 32; break;
        case 3: W = W3; bias = b3; O = O3; ostr = 32; break;
        case 4: W = W4; bias = b4; O = O4; ostr = 64; break;
        default: W = W5; bias = b5; O = O5; ostr = 64; break;
    }
    const int tid = threadIdx.x;
    const int m0 = blockIdx.x * 32;

    {
        const float4* Wg = (const float4*)W;
        float4* Wl = (float4*)Wsh;
        #pragma unroll
        for (int i = 0; i < 16; ++i) Wl[tid + i * 256] = Wg[tid + i * 256];
    }
    {
        float4* Xl = (float4*)Xs;
        const float4* Xg = (const float4*)X;
        #pragma unroll
        for (int i = 0; i < 4; ++i) {
            int f = tid + i * 256;
            int r = f >> 5, c4 = f & 31;
            int row = m0 + r;
            float4 val = make_float4(0.f, 0.f, 0.f, 0.f);
            if (row < M) val = Xg[(size_t)row * 32 + c4];
            Xl[f] = val;
        }
    }
    __syncthreads();

    const int tr = tid >> 5, tc = tid & 31;
    const int r0 = tr * 4, c0 = tc * 4;
    float acc[4][4] = {};
    #pragma unroll 4
    for (int kk = 0; kk < 128; ++kk) {
        float4 bb = *(const float4*)&Wsh[kk * 128 + c0];
        #pragma unroll
        for (int i = 0; i < 4; ++i) {
            float a = Xs[(r0 + i) * 128 + kk];
            acc[i][0] += a * bb.x; acc[i][1] += a * bb.y;
            acc[i][2] += a * bb.z; acc[i][3] += a * bb.w;
        }
    }
    float4 bias4 = *(const float4*)&bias[c0];
    #pragma unroll
    for (int i = 0; i < 4; ++i) {
        int row = m0 + r0 + i;
        if (row < M) {
            float4 o;
            o.x = acc[i][0] + bias4.x; o.y = acc[i][1] + bias4.y;
            o.z = acc[i][2] + bias4.z; o.w = acc[i][3] + bias4.w;
            ((float4*)O)[(size_t)row * ostr + tc] = o;
        }
    }
}

// ======================= node-centric attention ==========================
// One 32-lane group per node; edges processed in chunks of 4 so all gather
// loads (k,v,msg x4) are in flight before the shuffle reductions (4
// independent chains -> latency hidden by ILP).
__global__ __launch_bounds__(256) void node_attn_kernel(
    const int* __restrict__ row_start, const int2* __restrict__ se,
    const float* __restrict__ relp, const float* __restrict__ msg,
    const float* __restrict__ time_w, const float* __restrict__ time_b,
    const float* __restrict__ q, const float* __restrict__ k,
    const float* __restrict__ v, const float* __restrict__ u,
    const float* __restrict__ We, const float* __restrict__ skip,
    float* __restrict__ outp, float* __restrict__ bn_sum, float* __restrict__ bn_ssq,
    int N, int do_bn)
{
    __shared__ float WeS[96 * 128];   // 48 KB
    const int tid = threadIdx.x;
    {
        const float4* Wg = (const float4*)We;
        float4* Wl = (float4*)WeS;
        #pragma unroll
        for (int i = 0; i < 12; ++i) Wl[tid + i * 256] = Wg[tid + i * 256];
    }
    const int g = tid >> 5, l = tid & 31;
    const float twl = time_w[l];
    const float tbl = time_b[l];
    __syncthreads();

    const float4* K4 = (const float4*)k;
    const float4* V4 = (const float4*)v;
    const float4* Q4 = (const float4*)q;
    const float4* U4 = (const float4*)u;
    const float2* M2 = (const float2*)msg;
    const float4* S4 = (const float4*)skip;
    const float4* WeS4 = (const float4*)WeS;

    float4 bsum = {0,0,0,0}, bssq = {0,0,0,0};

    for (int n = blockIdx.x * 8 + g; n < N; n += gridDim.x * 8) {
        const int e0 = row_start[n], e1 = row_start[n + 1];
        const float4 q4 = Q4[(size_t)n * 32 + l];
        const float4 u0 = U4[(size_t)n * 64 + l];
        const float4 u1 = U4[(size_t)n * 64 + 32 + l];
        float4 wv = {0,0,0,0};
        float sea0x = 0.f, sea0y = 0.f, sea0z = 0.f;
        float sea1x = 0.f, sea1y = 0.f, sea1z = 0.f;
        float den0 = 0.f, den1 = 0.f;

        for (int base = e0; base < e1; base += 4) {
            int   srcs[4], eids[4];
            float rels[4];
            #pragma unroll
            for (int j = 0; j < 4; ++j) {
                int idx = base + j;
                idx = (idx < e1) ? idx : (e1 - 1);
                int2 s2 = se[idx];
                srcs[j] = s2.x; eids[j] = s2.y;
                rels[j] = relp[idx];
            }
            // issue all gathers up front (12 loads in flight)
            float4 k4v[4], v4v[4];
            float2 m2v[4];
            #pragma unroll
            for (int j = 0; j < 4; ++j) {
                k4v[j] = K4[(size_t)srcs[j] * 32 + l];
                v4v[j] = V4[(size_t)srcs[j] * 32 + l];
                m2v[j] = M2[(size_t)eids[j] * 32 + l];
            }
            float eac[4], pq[4], pa[4], pb[4];
            #pragma unroll
            for (int j = 0; j < 4; ++j)
                eac[j] = cosf(rels[j] * twl + tbl);
            #pragma unroll
            for (int j = 0; j < 4; ++j) {
                pq[j] = q4.x*k4v[j].x + q4.y*k4v[j].y + q4.z*k4v[j].z + q4.w*k4v[j].w;
                pa[j] = eac[j]*u0.x + m2v[j].x*u0.y + m2v[j].y*u0.z;
                pb[j] = eac[j]*u1.x + m2v[j].x*u1.y + m2v[j].y*u1.z;
            }
            // 4 independent butterfly chains
            #pragma unroll
            for (int s = 1; s <= 8; s <<= 1) {
                #pragma unroll
                for (int j = 0; j < 4; ++j) pq[j] += __shfl_xor(pq[j], s);
            }
            float pqo[4];
            #pragma unroll
            for (int j = 0; j < 4; ++j) pqo[j] = __shfl_xor(pq[j], 16);
            #pragma unroll
            for (int s = 1; s <= 16; s <<= 1) {
                #pragma unroll
                for (int j = 0; j < 4; ++j) {
                    pa[j] += __shfl_xor(pa[j], s);
                    pb[j] += __shfl_xor(pb[j], s);
                }
            }
            #pragma unroll
            for (int j = 0; j < 4; ++j) {
                const float qk0 = (l < 16) ? pq[j] : pqo[j];
                const float qk1 = (l < 16) ? pqo[j] : pq[j];
                float w0 = __expf((qk0 + pa[j]) * 0.125f);
                float w1 = __expf((qk1 + pb[j]) * 0.125f);
                if (base + j >= e1) { w0 = 0.f; w1 = 0.f; }
                den0 += w0; den1 += w1;
                const float wh = (l < 16) ? w0 : w1;
                wv.x += wh*v4v[j].x; wv.y += wh*v4v[j].y;
                wv.z += wh*v4v[j].z; wv.w += wh*v4v[j].w;
                sea0x += w0*eac[j]; sea0y += w0*m2v[j].x; sea0z += w0*m2v[j].y;
                sea1x += w1*eac[j]; sea1y += w1*m2v[j].x; sea1z += w1*m2v[j].y;
            }
        }

        // e_fin[c] = sum_j sea_h[j] * We[j][h*64+c]  (lane's 4 channels)
        float4 ef = {0,0,0,0};
        #pragma unroll
        for (int j = 0; j < 96; ++j) {
            const int owner = (j < 32) ? j : ((j - 32) >> 1);
            float c0, c1;
            if (j < 32)                    { c0 = sea0x; c1 = sea1x; }
            else if (((j - 32) & 1) == 0)  { c0 = sea0y; c1 = sea1y; }
            else                           { c0 = sea0z; c1 = sea1z; }
            const float s0 = __shfl(c0, owner, 32);
            const float s1 = __shfl(c1, owner, 32);
            const float sj = (l < 16) ? s0 : s1;
            const float4 w4 = WeS4[j * 32 + l];
            ef.x += sj*w4.x; ef.y += sj*w4.y; ef.z += sj*w4.z; ef.w += sj*w4.w;
        }

        const float dh = (l < 16) ? den0 : den1;
        const float4 s4 = S4[(size_t)n * 32 + l];
        float4 o;
        if (dh > 0.f) {
            const float r = 1.0f / dh;
            o.x = (wv.x + ef.x) * r + s4.x;
            o.y = (wv.y + ef.y) * r + s4.y;
            o.z = (wv.z + ef.z) * r + s4.z;
            o.w = (wv.w + ef.w) * r + s4.w;
        } else {
            o = s4;
        }
        ((float4*)outp)[(size_t)n * 32 + l] = o;
        if (do_bn) {
            bsum.x += o.x; bsum.y += o.y; bsum.z += o.z; bsum.w += o.w;
            bssq.x += o.x*o.x; bssq.y += o.y*o.y; bssq.z += o.z*o.z; bssq.w += o.w*o.w;
        }
    }

    if (do_bn) {
        __syncthreads();                 // WeS no longer needed: reuse as scratch
        float* red = WeS;
        const int t8 = tid * 8;
        red[t8+0]=bsum.x; red[t8+1]=bsum.y; red[t8+2]=bsum.z; red[t8+3]=bsum.w;
        red[t8+4]=bssq.x; red[t8+5]=bssq.y; red[t8+6]=bssq.z; red[t8+7]=bssq.w;
        __syncthreads();
        if (g == 0) {
            float a[8] = {0,0,0,0,0,0,0,0};
            for (int gg = 0; gg < 8; ++gg) {
                const float* r2 = &red[(gg*32 + l)*8];
                #pragma unroll
                for (int kk = 0; kk < 8; ++kk) a[kk] += r2[kk];
            }
            #pragma unroll
            for (int kk = 0; kk < 4; ++kk) {
                atomicAdd(&bn_sum[4*l + kk], a[kk]);
                atomicAdd(&bn_ssq[4*l + kk], a[4 + kk]);
            }
        }
    }
}

// ======================= BN =======================
__global__ void bn_stats_kernel(const float* __restrict__ bn_sum,
                                const float* __restrict__ bn_ssq,
                                float* __restrict__ mu, float* __restrict__ inv, int N)
{
    int c = threadIdx.x;
    float m = bn_sum[c] / (float)N;
    float var = bn_ssq[c] / (float)N - m * m;
    var = fmaxf(var, 0.f);
    mu[c] = m;
    inv[c] = rsqrtf(var + 1e-5f);
}

__global__ __launch_bounds__(256) void bn_apply_kernel(
    const float* __restrict__ pre, const float* __restrict__ mu,
    const float* __restrict__ inv, const float* __restrict__ gw,
    const float* __restrict__ bw, float* __restrict__ h, size_t total)
{
    size_t i = (size_t)blockIdx.x * 256 + threadIdx.x;
    const size_t stride = (size_t)gridDim.x * 256;
    for (; i < total; i += stride) {
        int c = (int)(i & 127);
        float val = (pre[i] - mu[c]) * inv[c] * gw[c] + bw[c];
        h[i] = fmaxf(val, 0.f);
    }
}

// =========================================================================
extern "C" void kernel_launch(void* const* d_in, const int* in_sizes, int n_in,
                              void* d_out, int out_size, void* d_ws, size_t ws_size,
                              hipStream_t stream)
{
    const float* x   = (const float*)d_in[0];
    const float* lu  = (const float*)d_in[1];
    const int*   ei  = (const int*)d_in[2];
    const float* t   = (const float*)d_in[3];
    const float* msg = (const float*)d_in[4];
    const float* tw  = (const float*)d_in[5];
    const float* tb  = (const float*)d_in[6];
    const float* bng = (const float*)d_in[7];
    const float* bnb = (const float*)d_in[8];
    const float* Wq1 = (const float*)d_in[9];  const float* bq1 = (const float*)d_in[10];
    const float* Wk1 = (const float*)d_in[11]; const float* bk1 = (const float*)d_in[12];
    const float* Wv1 = (const float*)d_in[13]; const float* bv1 = (const float*)d_in[14];
    const float* We1 = (const float*)d_in[15];
    const float* Ws1 = (const float*)d_in[16]; const float* bs1 = (const float*)d_in[17];
    const float* Wq2 = (const float*)d_in[18]; const float* bq2 = (const float*)d_in[19];
    const float* Wk2 = (const float*)d_in[20]; const float* bk2 = (const float*)d_in[21];
    const float* Wv2 = (const float*)d_in[22]; const float* bv2 = (const float*)d_in[23];
    const float* We2 = (const float*)d_in[24];
    const float* Ws2 = (const float*)d_in[25]; const float* bs2 = (const float*)d_in[26];

    const int N = in_sizes[0] / DD;
    const int E = in_sizes[3];
    const size_t NM = (size_t)N * DD;

    float* ws  = (float*)d_ws;
    float* qb  = ws;
    float* kb  = ws + NM;
    float* vb  = ws + 2 * NM;
    float* sb  = ws + 3 * NM;
    float* ub  = ws + 4 * NM;        // 2*NM: [N][2][32] float4
    float* pre = ws + 6 * NM;        // layer-1 pre-BN out; BN applied in place
    float* relp = ws + 7 * NM;       // E floats
    int2*  se   = (int2*)(relp + E); // E int2 (src, eid), 8B-aligned
    float* Wu   = (float*)(se + E);  // 2*128*128
    float* bu   = Wu + 32768;        // 256
    float* bsum = bu + 256;          // 128
    float* bssq = bsum + 128;        // 128
    float* muv  = bssq + 128;        // 128
    float* invv = muv + 128;         // 128
    int* cnt       = (int*)(invv + 128);
    int* row_start = cnt + N;        // N+1
    int* cursor    = row_start + N + 1;

    const int EB = (E + 255) / 256;

    // ---- CSR (shared by both layers) ----
    hipMemsetAsync(cnt, 0, (size_t)N * sizeof(int), stream);
    hist_kernel<<<EB, 256, 0, stream>>>(ei, cnt, E);
    scan_kernel<<<1, 1024, 0, stream>>>(cnt, row_start, cursor, N);
    scatter_kernel<<<EB, 256, 0, stream>>>(ei, lu, t, cursor, se, relp, E);

    dim3 gemmGrid((N + 31) / 32, 6);

    // ---------------- layer 1 ----------------
    build_wu_kernel<<<128, 256, 0, stream>>>(Wq1, bq1, We1, Wu, bu);
    gemm6_kernel<<<gemmGrid, 256, 0, stream>>>(
        x, Wq1, Wk1, Wv1, Ws1, Wu, Wu + 16384,
        bq1, bk1, bv1, bs1, bu, bu + 128,
        qb, kb, vb, sb, ub, ub + 128, N);
    hipMemsetAsync(bsum, 0, 256 * sizeof(float), stream);
    node_attn_kernel<<<2048, 256, 0, stream>>>(
        row_start, se, relp, msg, tw, tb,
        qb, kb, vb, ub, We1, sb, pre, bsum, bssq, N, 1);
    bn_stats_kernel<<<1, 128, 0, stream>>>(bsum, bssq, muv, invv, N);
    bn_apply_kernel<<<2048, 256, 0, stream>>>(pre, muv, invv, bng, bnb, pre, NM);

    // ---------------- layer 2 ----------------
    build_wu_kernel<<<128, 256, 0, stream>>>(Wq2, bq2, We2, Wu, bu);
    gemm6_kernel<<<gemmGrid, 256, 0, stream>>>(
        pre, Wq2, Wk2, Wv2, Ws2, Wu, Wu + 16384,
        bq2, bk2, bv2, bs2, bu, bu + 128,
        qb, kb, vb, sb, ub, ub + 128, N);
    node_attn_kernel<<<2048, 256, 0, stream>>>(
        row_start, se, relp, msg, tw, tb,
        qb, kb, vb, ub, We2, sb, (float*)d_out, nullptr, nullptr, N, 0);
}